// Round 8
// baseline (256.113 us; speedup 1.0000x reference)
//
#include <hip/hip_runtime.h>
#include <hip/hip_fp16.h>
#include <math.h>

// ---------------------------------------------------------------------------
// GCN 2-layer + two heads, fp32 in/out, MI355X.
//   R13 (= R12 with nt-store compile fix): 5 dispatches, lean-VGPR fused aggs.
//   - 32 nodes per fused-agg block, phase-2 B-fragments hoisted over a 2-tile
//     loop -> W L2 streaming halved (600 -> 300 MB), better skew statistics.
//   - phase-2 A-fragments in LDS f16 hi/lo tiles -> VGPR stays at phase-1
//     level, occupancy preserved (R10 lesson).
//   - nontemporal stores (via clang ext_vector floatx4, NOT HIP float4) for
//     out_h/out_v/out_t -> stop evicting the gather table from L2.
// ---------------------------------------------------------------------------

#define DFEAT 128
#define BSH 8            // bucket = dst >> 8 (256 nodes/bucket)
#define BKE 4096         // edges per partition block
#define SLABCAP 4608     // bucket slab capacity: mean 4096 + 8 sigma

using half8   = __attribute__((ext_vector_type(8))) _Float16;
using floatx4 = __attribute__((ext_vector_type(4))) float;

__device__ __forceinline__ void split_f16(float x, _Float16& hi, _Float16& lo) {
    _Float16 h = (_Float16)x;
    hi = h;
    lo = (_Float16)(x - (float)h);
}

__device__ __forceinline__ void nt_store4(float* p, float a, float b, float c, float d) {
    floatx4 v = {a, b, c, d};
    __builtin_nontemporal_store(v, (floatx4*)p);
}
__device__ __forceinline__ void nt_store1(float* p, float v) {
    __builtin_nontemporal_store(v, p);
}

// ---------------- K1: W pre-split to f16 frags  +  slab partition -----------
__global__ __launch_bounds__(256) void prep_part_k(const int* __restrict__ src,
                                                   const int* __restrict__ dst,
                                                   int* __restrict__ cursor,
                                                   unsigned* __restrict__ pk_out,
                                                   const float* __restrict__ W0,
                                                   const float* __restrict__ W1,
                                                   const float* __restrict__ W2,
                                                   const float* __restrict__ W3,
                                                   _Float16* __restrict__ hi_all,
                                                   _Float16* __restrict__ lo_all,
                                                   int E, int nbuk) {
    int tid = threadIdx.x;
    if (blockIdx.x < 256) {
        int pb = blockIdx.x;
        int b = pb >> 6;
        const float* W = (b == 0) ? W0 : (b == 1) ? W1 : (b == 2) ? W2 : W3;
        _Float16* hi = hi_all + (size_t)b * 16384;
        _Float16* lo = lo_all + (size_t)b * 16384;
        int i = (pb & 63) * 256 + tid;
        int j = i & 7;
        int lane = (i >> 3) & 63;
        int ts = i >> 9;
        int s = ts & 3, t = ts >> 2;
        int k = s * 32 + (lane >> 4) * 8 + j;
        int n = t * 16 + (lane & 15);
        split_f16(W[k * 128 + n], hi[i], lo[i]);
        return;
    }

    // ---- partition body ----
    __shared__ int h[256];
    __shared__ int base[256];
    h[tid] = 0;
    __syncthreads();
    int B = blockIdx.x - 256;
    int e0 = B * BKE;

    unsigned pk[16];
    unsigned short rk[16];
    unsigned char bk[16];
    int m = 0;
#pragma unroll
    for (int it = 0; it < 4; ++it) {
        int e = e0 + it * 1024 + tid * 4;
        if (e + 3 < E) {
            int4 d4 = *(const int4*)(dst + e);
            int4 s4 = *(const int4*)(src + e);
            int dd[4] = {d4.x, d4.y, d4.z, d4.w};
            int ss[4] = {s4.x, s4.y, s4.z, s4.w};
#pragma unroll
            for (int k = 0; k < 4; ++k) {
                int b = dd[k] >> BSH;
                pk[m] = ((unsigned)dd[k] << 16) | (unsigned)ss[k];
                rk[m] = (unsigned short)atomicAdd(&h[b], 1);
                bk[m] = (unsigned char)b;
                ++m;
            }
        } else {
            for (int k = 0; k < 4; ++k) {
                if (e + k < E) {
                    int d = dst[e + k], sv = src[e + k];
                    int b = d >> BSH;
                    pk[m] = ((unsigned)d << 16) | (unsigned)sv;
                    rk[m] = (unsigned short)atomicAdd(&h[b], 1);
                    bk[m] = (unsigned char)b;
                    ++m;
                }
            }
        }
    }
    __syncthreads();
    if (tid < nbuk && h[tid]) base[tid] = tid * SLABCAP + atomicAdd(&cursor[tid], h[tid]);
    __syncthreads();
    for (int j2 = 0; j2 < m; ++j2)
        pk_out[base[bk[j2]] + (int)rk[j2]] = pk[j2];
}

// ---------------- CSR build from slabs (counts live in cursor) --------------
__device__ __forceinline__ void csr_body(const unsigned* __restrict__ pk_arr,
                                         const int* __restrict__ cursor,
                                         int* __restrict__ row_ptr,
                                         unsigned short* __restrict__ col_idx,
                                         float* __restrict__ dinv,
                                         int N, int E, int nbuk, int b) {
    __shared__ int hcnt[256];
    __shared__ int esc[256];
    __shared__ int sx[256];
    int tid = threadIdx.x;

    int v = (tid < nbuk) ? cursor[tid] : 0;
    sx[tid] = v;
    __syncthreads();
    int x = v;
    for (int o = 1; o < 256; o <<= 1) {
        int y = (tid >= o) ? sx[tid - o] : 0;
        __syncthreads();
        x += y;
        sx[tid] = x;
        __syncthreads();
    }
    int s0 = (b > 0) ? sx[b - 1] : 0;
    int cnt = sx[b] - s0;
    __syncthreads();

    hcnt[tid] = 0;
    __syncthreads();

    const unsigned* slab = pk_arr + (size_t)b * SLABCAP;
    unsigned p[20];
    unsigned short r[20];
    int m = 0;
    for (int i = tid; i < cnt; i += 256) {
        unsigned pp = slab[i];
        int d = (pp >> 16) & 255;
        r[m] = (unsigned short)atomicAdd(&hcnt[d], 1);
        p[m] = pp;
        ++m;
    }
    __syncthreads();

    int hv = hcnt[tid];
    esc[tid] = hv;
    __syncthreads();
    int hx = hv;
    for (int o = 1; o < 256; o <<= 1) {
        int y = (tid >= o) ? esc[tid - o] : 0;
        __syncthreads();
        hx += y;
        esc[tid] = hx;
        __syncthreads();
    }
    int excl = hx - hv;
    __syncthreads();
    esc[tid] = excl;
    __syncthreads();

    int node = (b << BSH) + tid;
    if (node < N) {
        row_ptr[node] = s0 + excl;
        dinv[node] = rsqrtf((float)(hv + 1));   // +1 self loop
    }
    if (node == N) row_ptr[N] = E;

    for (int j = 0; j < m; ++j) {
        int d = (p[j] >> 16) & 255;
        col_idx[s0 + esc[d] + (int)r[j]] = (unsigned short)(p[j] & 0xFFFFu);
    }
}

// ---------------- GEMM pieces (split-f16 MFMA, prepped fragments) -----------
__device__ __forceinline__ void stage_frags(const _Float16* __restrict__ Whi,
                                            const _Float16* __restrict__ Wlo,
                                            _Float16* __restrict__ WhiS,
                                            _Float16* __restrict__ WloS) {
    const int tid = threadIdx.x;
#pragma unroll
    for (int j = 0; j < 8; ++j)
        ((float4*)WhiS)[tid + j * 256] = ((const float4*)Whi)[tid + j * 256];
#pragma unroll
    for (int j = 0; j < 8; ++j)
        ((float4*)WloS)[tid + j * 256] = ((const float4*)Wlo)[tid + j * 256];
}

template <typename InT>
__device__ __forceinline__ void load_A(const InT* __restrict__ X, int M, int m0,
                                       half8 (&Ahi)[2][4], half8 (&Alo)[2][4]) {
    const int lane = threadIdx.x & 63;
    const int quad = lane >> 4, l16 = lane & 15;
#pragma unroll
    for (int r = 0; r < 2; ++r) {
        int row = m0 + r * 16 + l16;
        row = row < M ? row : (M - 1);
        const InT* xr = X + (size_t)row * 128 + quad * 8;
#pragma unroll
        for (int s = 0; s < 4; ++s) {
            if constexpr (sizeof(InT) == 2) {
                Ahi[r][s] = *(const half8*)(xr + s * 32);   // exact
            } else {
                float4 a = ((const float4*)(xr + s * 32))[0];
                float4 b = ((const float4*)(xr + s * 32))[1];
                float v[8] = {a.x, a.y, a.z, a.w, b.x, b.y, b.z, b.w};
#pragma unroll
                for (int j = 0; j < 8; ++j) {
                    _Float16 hi, lo;
                    split_f16(v[j], hi, lo);
                    Ahi[r][s][j] = hi;
                    Alo[r][s][j] = lo;
                }
            }
        }
    }
}

template <typename OutT, int TERMS, bool BIAS, bool RELU>
__device__ __forceinline__ void mfma_store(half8 (&Ahi)[2][4], half8 (&Alo)[2][4],
                                           const _Float16* __restrict__ WhiS,
                                           const _Float16* __restrict__ WloS,
                                           const float* __restrict__ bias,
                                           OutT* __restrict__ Y, int M, int m0) {
    const int lane = threadIdx.x & 63;
    const int quad = lane >> 4, l16 = lane & 15;

    floatx4 acc[2][8];
#pragma unroll
    for (int r = 0; r < 2; ++r)
#pragma unroll
        for (int t = 0; t < 8; ++t) acc[r][t] = (floatx4){0.f, 0.f, 0.f, 0.f};

    const half8* WH = (const half8*)WhiS;
    const half8* WL = (const half8*)WloS;
#pragma unroll
    for (int s = 0; s < 4; ++s) {
#pragma unroll
        for (int t = 0; t < 8; ++t) {
            half8 bh = WH[(t * 4 + s) * 64 + lane];
            half8 bl = WL[(t * 4 + s) * 64 + lane];
#pragma unroll
            for (int r = 0; r < 2; ++r) {
                acc[r][t] = __builtin_amdgcn_mfma_f32_16x16x32_f16(Ahi[r][s], bh, acc[r][t], 0, 0, 0);
                if constexpr (TERMS == 3)
                    acc[r][t] = __builtin_amdgcn_mfma_f32_16x16x32_f16(Alo[r][s], bh, acc[r][t], 0, 0, 0);
                acc[r][t] = __builtin_amdgcn_mfma_f32_16x16x32_f16(Ahi[r][s], bl, acc[r][t], 0, 0, 0);
            }
        }
    }

    float bcol[8];
    if (BIAS) {
#pragma unroll
        for (int t = 0; t < 8; ++t) bcol[t] = bias[t * 16 + l16];
    }
#pragma unroll
    for (int r = 0; r < 2; ++r) {
#pragma unroll
        for (int e = 0; e < 4; ++e) {
            int row = m0 + r * 16 + quad * 4 + e;
            if (row < M) {
                OutT* yr = Y + (size_t)row * 128 + l16;
#pragma unroll
                for (int t = 0; t < 8; ++t) {
                    float v = acc[r][t][e];
                    if (BIAS) v += bcol[t];
                    if (RELU) v = fmaxf(v, 0.f);
                    if constexpr (sizeof(OutT) == 4) yr[t * 16] = v;
                    else yr[t * 16] = __float2half(v);
                }
            }
        }
    }
}

// ---------------- K2: fused CSR build + layer-0 GEMM ------------------------
__global__ __launch_bounds__(256) void csrgemm_k(const unsigned* __restrict__ pk_arr,
                                                 const int* __restrict__ cursor,
                                                 int* __restrict__ row_ptr,
                                                 unsigned short* __restrict__ col_idx,
                                                 float* __restrict__ dinv,
                                                 const float* __restrict__ X,
                                                 const _Float16* __restrict__ Whi,
                                                 const _Float16* __restrict__ Wlo,
                                                 __half* __restrict__ hs,
                                                 int N, int E, int nbuk) {
    if ((int)blockIdx.x < nbuk) {
        csr_body(pk_arr, cursor, row_ptr, col_idx, dinv, N, E, nbuk, blockIdx.x);
        return;
    }
    __shared__ _Float16 WhiS[16384];
    __shared__ _Float16 WloS[16384];
    stage_frags(Whi, Wlo, WhiS, WloS);
    half8 Ahi[2][4], Alo[2][4];
    int m0 = (blockIdx.x - nbuk) * 128 + ((threadIdx.x >> 6) << 5);
    load_A<float>(X, N, m0, Ahi, Alo);
    __syncthreads();
    mfma_store<__half, 3, false, false>(Ahi, Alo, WhiS, WloS, nullptr, hs, N, m0);
}

// ---------------- K3: fused weighted agg + layer-1 GEMM ---------------------
// Block owns 32 consecutive nodes (one per 16-lane group, 2 halves).
// Phase 1: weighted aggregate (8-deep batches, consume-time weight shfl,
// epilogue bias) -> padded LDS f16 tile (32 rows). Phase 2: two 16-row
// 2-term f16 GEMM tiles sharing each streamed B-fragment (halves W traffic).
#define LP16 136   // f16 elems per LDS row (272B stride -> 2-way banks)
__global__ __launch_bounds__(256, 8) void agg0gemm1_k(const __half* __restrict__ hs,
                                                      const int* __restrict__ row_ptr,
                                                      const unsigned short* __restrict__ col_idx,
                                                      const float* __restrict__ dinv,
                                                      const float* __restrict__ bias,
                                                      const _Float16* __restrict__ W1hi,
                                                      const _Float16* __restrict__ W1lo,
                                                      __half* __restrict__ out_hs, int n) {
    __shared__ _Float16 A[32 * LP16];
    const int tid = threadIdx.x;
    const int c = tid & 15;
    const int g = tid >> 4;
    const int gbase = tid & 48;

#pragma unroll
    for (int hf = 0; hf < 2; ++hf) {
        int i = blockIdx.x * 32 + hf * 16 + g;
        int rl = (hf * 16 + g) * LP16 + c * 8;
        if (i < n) {
            float di = dinv[i];
            float acc[8];
            {
                uint4 raw = ((const uint4*)(hs + (size_t)i * DFEAT))[c];
                const __half2* hp = (const __half2*)&raw;
#pragma unroll
                for (int k = 0; k < 4; ++k) {
                    float2 f = __half22float2(hp[k]);
                    acc[2 * k] = f.x * di; acc[2 * k + 1] = f.y * di;
                }
            }
            int rs = row_ptr[i];
            int cnt = row_ptr[i + 1] - rs;

            for (int base = 0; base < cnt; base += 16) {
                int t = base + c;
                int idx = (t < cnt) ? (int)col_idx[rs + t] : 0;
                float dv = (t < cnt) ? dinv[idx] : 0.f;
                int lim = cnt - base; if (lim > 16) lim = 16;
#pragma unroll
                for (int h = 0; h < 2; ++h) {
                    int l0 = h * 8;
                    if (l0 < lim) {
                        uint4 vv[8];
#pragma unroll
                        for (int q = 0; q < 8; ++q) {
                            int ia = __shfl(idx, gbase + l0 + q);
                            if (l0 + q < lim)
                                vv[q] = ((const uint4*)(hs + (size_t)ia * DFEAT))[c];
                        }
#pragma unroll
                        for (int q = 0; q < 8; ++q) {
                            if (l0 + q < lim) {
                                float wq = __shfl(dv, gbase + l0 + q);
                                const __half2* pq = (const __half2*)&vv[q];
#pragma unroll
                                for (int k = 0; k < 4; ++k) {
                                    float2 f = __half22float2(pq[k]);
                                    acc[2 * k]     = fmaf(f.x, wq, acc[2 * k]);
                                    acc[2 * k + 1] = fmaf(f.y, wq, acc[2 * k + 1]);
                                }
                            }
                        }
                    }
                }
            }

            float4 b0 = ((const float4*)bias)[c * 2];
            float4 b1 = ((const float4*)bias)[c * 2 + 1];
            float o[8];
            o[0] = fmaf(acc[0], di, b0.x); o[1] = fmaf(acc[1], di, b0.y);
            o[2] = fmaf(acc[2], di, b0.z); o[3] = fmaf(acc[3], di, b0.w);
            o[4] = fmaf(acc[4], di, b1.x); o[5] = fmaf(acc[5], di, b1.y);
            o[6] = fmaf(acc[6], di, b1.z); o[7] = fmaf(acc[7], di, b1.w);
            _Float16 hv[8];
#pragma unroll
            for (int k = 0; k < 8; ++k) hv[k] = (_Float16)(fmaxf(o[k], 0.f) * di);
            *(uint4*)(&A[rl]) = *(uint4*)hv;
        } else {
            uint4 z = {0u, 0u, 0u, 0u};
            *(uint4*)(&A[rl]) = z;
        }
    }

    __syncthreads();

    // ---- phase 2: two 16-row tiles share each streamed B fragment ----
    const int lane = tid & 63, wave = tid >> 6;
    const int quad = lane >> 4, l16 = lane & 15;

    floatx4 acc2[2][2];
#pragma unroll
    for (int tile = 0; tile < 2; ++tile) {
        acc2[tile][0] = (floatx4){0.f, 0.f, 0.f, 0.f};
        acc2[tile][1] = (floatx4){0.f, 0.f, 0.f, 0.f};
    }
#pragma unroll
    for (int s = 0; s < 4; ++s) {
#pragma unroll
        for (int tt = 0; tt < 2; ++tt) {
            int t = wave * 2 + tt;
            half8 bh = *(const half8*)(W1hi + ((size_t)((t * 4 + s) * 64 + lane)) * 8);
            half8 bl = *(const half8*)(W1lo + ((size_t)((t * 4 + s) * 64 + lane)) * 8);
#pragma unroll
            for (int tile = 0; tile < 2; ++tile) {
                half8 a = *(const half8*)(&A[(tile * 16 + l16) * LP16 + s * 32 + quad * 8]);
                acc2[tile][tt] = __builtin_amdgcn_mfma_f32_16x16x32_f16(a, bh, acc2[tile][tt], 0, 0, 0);
                acc2[tile][tt] = __builtin_amdgcn_mfma_f32_16x16x32_f16(a, bl, acc2[tile][tt], 0, 0, 0);
            }
        }
    }
#pragma unroll
    for (int tile = 0; tile < 2; ++tile) {
#pragma unroll
        for (int tt = 0; tt < 2; ++tt) {
            int col = (wave * 2 + tt) * 16 + l16;
#pragma unroll
            for (int e = 0; e < 4; ++e) {
                int row = blockIdx.x * 32 + tile * 16 + quad * 4 + e;
                if (row < n)
                    out_hs[(size_t)row * DFEAT + col] = __float2half(acc2[tile][tt][e]);
            }
        }
    }
}

// ---------------- K4: fused plain agg + heads -------------------------------
// Block owns 32 nodes. Phase 1: unweighted aggregate, nt-write out_h, split
// rows into LDS f16 hi/lo tiles. Phase 2: heads sequential; per head two
// 16-row tiles share each streamed B fragment; A read per-MFMA from LDS
// (register footprint stays at phase-1 level).
__global__ __launch_bounds__(256, 8) void agg1heads_k(const __half* __restrict__ hs,
                                                      const int* __restrict__ row_ptr,
                                                      const unsigned short* __restrict__ col_idx,
                                                      const float* __restrict__ dinv,
                                                      const float* __restrict__ bias,
                                                      const _Float16* __restrict__ WvHi,
                                                      const _Float16* __restrict__ WvLo,
                                                      const _Float16* __restrict__ WtHi,
                                                      const _Float16* __restrict__ WtLo,
                                                      const float* __restrict__ bv,
                                                      const float* __restrict__ bt,
                                                      float* __restrict__ out_h,
                                                      float* __restrict__ out_v,
                                                      float* __restrict__ out_t, int n) {
    __shared__ _Float16 AHi[32 * LP16];
    __shared__ _Float16 ALo[32 * LP16];
    const int tid = threadIdx.x;
    const int c = tid & 15;
    const int g = tid >> 4;
    const int gbase = tid & 48;

#pragma unroll
    for (int hf = 0; hf < 2; ++hf) {
        int i = blockIdx.x * 32 + hf * 16 + g;
        int rl = (hf * 16 + g) * LP16 + c * 8;
        if (i < n) {
            float acc[8];
            {
                uint4 raw = ((const uint4*)(hs + (size_t)i * DFEAT))[c];
                const __half2* hp = (const __half2*)&raw;
#pragma unroll
                for (int k = 0; k < 4; ++k) {
                    float2 f = __half22float2(hp[k]);
                    acc[2 * k] = f.x; acc[2 * k + 1] = f.y;
                }
            }
            int rs = row_ptr[i];
            int cnt = row_ptr[i + 1] - rs;

            for (int base = 0; base < cnt; base += 16) {
                int t = base + c;
                int idx = (t < cnt) ? (int)col_idx[rs + t] : 0;
                int lim = cnt - base; if (lim > 16) lim = 16;
#pragma unroll
                for (int h = 0; h < 2; ++h) {
                    int l0 = h * 8;
                    if (l0 < lim) {
                        uint4 vv[8];
#pragma unroll
                        for (int q = 0; q < 8; ++q) {
                            int ia = __shfl(idx, gbase + l0 + q);
                            if (l0 + q < lim)
                                vv[q] = ((const uint4*)(hs + (size_t)ia * DFEAT))[c];
                        }
#pragma unroll
                        for (int q = 0; q < 8; ++q) {
                            if (l0 + q < lim) {
                                const __half2* pq = (const __half2*)&vv[q];
#pragma unroll
                                for (int k = 0; k < 4; ++k) {
                                    float2 f = __half22float2(pq[k]);
                                    acc[2 * k]     += f.x;
                                    acc[2 * k + 1] += f.y;
                                }
                            }
                        }
                    }
                }
            }

            float di = dinv[i];
            float4 b0 = ((const float4*)bias)[c * 2];
            float4 b1 = ((const float4*)bias)[c * 2 + 1];
            float o[8];
            o[0] = fmaf(acc[0], di, b0.x); o[1] = fmaf(acc[1], di, b0.y);
            o[2] = fmaf(acc[2], di, b0.z); o[3] = fmaf(acc[3], di, b0.w);
            o[4] = fmaf(acc[4], di, b1.x); o[5] = fmaf(acc[5], di, b1.y);
            o[6] = fmaf(acc[6], di, b1.z); o[7] = fmaf(acc[7], di, b1.w);
            nt_store4(out_h + (size_t)i * DFEAT + c * 8, o[0], o[1], o[2], o[3]);
            nt_store4(out_h + (size_t)i * DFEAT + c * 8 + 4, o[4], o[5], o[6], o[7]);
            _Float16 hhi[8], hlo[8];
#pragma unroll
            for (int k = 0; k < 8; ++k) split_f16(o[k], hhi[k], hlo[k]);
            *(uint4*)(&AHi[rl]) = *(uint4*)hhi;
            *(uint4*)(&ALo[rl]) = *(uint4*)hlo;
        } else {
            uint4 z = {0u, 0u, 0u, 0u};
            *(uint4*)(&AHi[rl]) = z;
            *(uint4*)(&ALo[rl]) = z;
        }
    }

    __syncthreads();

    // ---- phase 2: heads sequential; 2 tiles share each B fragment ----
    const int lane = tid & 63, wave = tid >> 6;
    const int quad = lane >> 4, l16 = lane & 15;

#pragma unroll
    for (int hd = 0; hd < 2; ++hd) {
        const _Float16* Hi = hd ? WtHi : WvHi;
        const _Float16* Lo = hd ? WtLo : WvLo;
        const float* bb    = hd ? bt : bv;
        float* outp        = hd ? out_t : out_v;

        floatx4 acc[2][2];
#pragma unroll
        for (int tile = 0; tile < 2; ++tile) {
            acc[tile][0] = (floatx4){0.f, 0.f, 0.f, 0.f};
            acc[tile][1] = (floatx4){0.f, 0.f, 0.f, 0.f};
        }
#pragma unroll
        for (int s = 0; s < 4; ++s) {
#pragma unroll
            for (int tt = 0; tt < 2; ++tt) {
                size_t fi = ((size_t)(((wave * 2 + tt) * 4 + s) * 64 + lane)) * 8;
                half8 bh = *(const half8*)(Hi + fi);
                half8 bl = *(const half8*)(Lo + fi);
#pragma unroll
                for (int tile = 0; tile < 2; ++tile) {
                    int al = (tile * 16 + l16) * LP16 + s * 32 + quad * 8;
                    half8 ahi = *(const half8*)(&AHi[al]);
                    half8 alo = *(const half8*)(&ALo[al]);
                    acc[tile][tt] = __builtin_amdgcn_mfma_f32_16x16x32_f16(ahi, bh, acc[tile][tt], 0, 0, 0);
                    acc[tile][tt] = __builtin_amdgcn_mfma_f32_16x16x32_f16(alo, bh, acc[tile][tt], 0, 0, 0);
                    acc[tile][tt] = __builtin_amdgcn_mfma_f32_16x16x32_f16(ahi, bl, acc[tile][tt], 0, 0, 0);
                }
            }
        }
#pragma unroll
        for (int tile = 0; tile < 2; ++tile) {
#pragma unroll
            for (int tt = 0; tt < 2; ++tt) {
                int col = (wave * 2 + tt) * 16 + l16;
                float bc = bb[col];
#pragma unroll
                for (int e = 0; e < 4; ++e) {
                    int row = blockIdx.x * 32 + tile * 16 + quad * 4 + e;
                    if (row < n)
                        nt_store1(outp + (size_t)row * DFEAT + col,
                                  fmaxf(acc[tile][tt][e] + bc, 0.f));
                }
            }
        }
    }
}

// ---------------------------------------------------------------------------

static inline size_t align_up(size_t x, size_t a) { return (x + a - 1) & ~(a - 1); }

extern "C" void kernel_launch(void* const* d_in, const int* in_sizes, int n_in,
                              void* d_out, int out_size, void* d_ws, size_t ws_size,
                              hipStream_t stream) {
    const float* x  = (const float*)d_in[0];
    const int*   ei = (const int*)d_in[1];
    const float* W0 = (const float*)d_in[2];
    const float* b0 = (const float*)d_in[3];
    const float* W1 = (const float*)d_in[4];
    const float* b1 = (const float*)d_in[5];
    const float* Wv = (const float*)d_in[6];
    const float* bv = (const float*)d_in[7];
    const float* Wt = (const float*)d_in[8];
    const float* bt = (const float*)d_in[9];

    const int N = in_sizes[0] / DFEAT;
    const int E = in_sizes[1] / 2;
    const int* src = ei;
    const int* dst = ei + E;
    const int nbuk = (N + 255) >> BSH;
    const int npb  = (E + BKE - 1) / BKE;
    const int gb   = (N + 127) / 128;
    const int fusB = (N + 31) / 32;

    // workspace carve-up
    char* w = (char*)d_ws;
    int* cursor      = (int*)w; w += align_up((size_t)256 * 4, 256);
    unsigned* pk_arr = (unsigned*)w; w += align_up((size_t)nbuk * SLABCAP * 4, 256);
    int* row_ptr     = (int*)w; w += align_up((size_t)(N + 1) * 4, 256);
    unsigned short* col_idx = (unsigned short*)w; w += align_up((size_t)E * 2, 256);
    float* dinv      = (float*)w; w += align_up((size_t)N * 4, 256);
    _Float16* whi_all = (_Float16*)w; w += align_up(4 * 16384 * 2, 256);
    _Float16* wlo_all = (_Float16*)w; w += align_up(4 * 16384 * 2, 256);
    __half* hs       = (__half*)w; w += align_up((size_t)N * DFEAT * 2, 256);
    __half* hs2      = (__half*)w; w += align_up((size_t)N * DFEAT * 2, 256);

    _Float16* w0hi = whi_all;            _Float16* w0lo = wlo_all;
    _Float16* w1hi = whi_all + 16384;    _Float16* w1lo = wlo_all + 16384;
    _Float16* wvhi = whi_all + 2*16384;  _Float16* wvlo = wlo_all + 2*16384;
    _Float16* wthi = whi_all + 3*16384;  _Float16* wtlo = wlo_all + 3*16384;

    float* out_h = (float*)d_out;
    float* out_v = out_h + (size_t)N * DFEAT;
    float* out_t = out_h + 2 * (size_t)N * DFEAT;

    hipMemsetAsync(cursor, 0, 256 * 4, stream);

    // K1: W prep + slab partition
    prep_part_k<<<256 + npb, 256, 0, stream>>>(src, dst, cursor, pk_arr,
                                               W0, W1, Wv, Wt, whi_all, wlo_all,
                                               E, nbuk);
    // K2: CSR build + unscaled layer-0 GEMM (co-resident)
    csrgemm_k<<<nbuk + gb, 256, 0, stream>>>(pk_arr, cursor, row_ptr, col_idx,
                                             dinv, x, w0hi, w0lo, hs, N, E, nbuk);
    // K3: weighted agg + layer-1 GEMM fused -> hs2
    agg0gemm1_k<<<fusB, 256, 0, stream>>>(hs, row_ptr, col_idx, dinv, b0,
                                          w1hi, w1lo, hs2, N);
    // K4: plain agg + both heads fused -> out_h, out_v, out_t
    agg1heads_k<<<fusB, 256, 0, stream>>>(hs2, row_ptr, col_idx, dinv, b1,
                                          wvhi, wvlo, wthi, wtlo, bv, bt,
                                          out_h, out_v, out_t, N);
}

// Round 9
// 239.754 us; speedup vs baseline: 1.0682x; 1.0682x over previous
//
#include <hip/hip_runtime.h>
#include <hip/hip_fp16.h>
#include <math.h>

// ---------------------------------------------------------------------------
// GCN 2-layer + two heads, fp32 in/out, MI355X.
//   R14 (= R13 minus nontemporal stores): 5 dispatches, lean-VGPR fused aggs.
//   - 32 nodes per fused-agg block, phase-2 B-fragments hoisted over a 2-tile
//     loop -> W L2 streaming halved.
//   - phase-2 A-fragments in LDS f16 hi/lo tiles -> VGPR ~32, occupancy kept.
//   - REGULAR stores everywhere: R13 measured nt stores doubling WRITE_SIZE
//     (75->160 MB) and +40 MB FETCH -> 55->91us regression. nt on partial
//     lines = write amplification on gfx950.
// ---------------------------------------------------------------------------

#define DFEAT 128
#define BSH 8            // bucket = dst >> 8 (256 nodes/bucket)
#define BKE 4096         // edges per partition block
#define SLABCAP 4608     // bucket slab capacity: mean 4096 + 8 sigma

using half8   = __attribute__((ext_vector_type(8))) _Float16;
using floatx4 = __attribute__((ext_vector_type(4))) float;

__device__ __forceinline__ void split_f16(float x, _Float16& hi, _Float16& lo) {
    _Float16 h = (_Float16)x;
    hi = h;
    lo = (_Float16)(x - (float)h);
}

// ---------------- K1: W pre-split to f16 frags  +  slab partition -----------
__global__ __launch_bounds__(256) void prep_part_k(const int* __restrict__ src,
                                                   const int* __restrict__ dst,
                                                   int* __restrict__ cursor,
                                                   unsigned* __restrict__ pk_out,
                                                   const float* __restrict__ W0,
                                                   const float* __restrict__ W1,
                                                   const float* __restrict__ W2,
                                                   const float* __restrict__ W3,
                                                   _Float16* __restrict__ hi_all,
                                                   _Float16* __restrict__ lo_all,
                                                   int E, int nbuk) {
    int tid = threadIdx.x;
    if (blockIdx.x < 256) {
        int pb = blockIdx.x;
        int b = pb >> 6;
        const float* W = (b == 0) ? W0 : (b == 1) ? W1 : (b == 2) ? W2 : W3;
        _Float16* hi = hi_all + (size_t)b * 16384;
        _Float16* lo = lo_all + (size_t)b * 16384;
        int i = (pb & 63) * 256 + tid;
        int j = i & 7;
        int lane = (i >> 3) & 63;
        int ts = i >> 9;
        int s = ts & 3, t = ts >> 2;
        int k = s * 32 + (lane >> 4) * 8 + j;
        int n = t * 16 + (lane & 15);
        split_f16(W[k * 128 + n], hi[i], lo[i]);
        return;
    }

    // ---- partition body ----
    __shared__ int h[256];
    __shared__ int base[256];
    h[tid] = 0;
    __syncthreads();
    int B = blockIdx.x - 256;
    int e0 = B * BKE;

    unsigned pk[16];
    unsigned short rk[16];
    unsigned char bk[16];
    int m = 0;
#pragma unroll
    for (int it = 0; it < 4; ++it) {
        int e = e0 + it * 1024 + tid * 4;
        if (e + 3 < E) {
            int4 d4 = *(const int4*)(dst + e);
            int4 s4 = *(const int4*)(src + e);
            int dd[4] = {d4.x, d4.y, d4.z, d4.w};
            int ss[4] = {s4.x, s4.y, s4.z, s4.w};
#pragma unroll
            for (int k = 0; k < 4; ++k) {
                int b = dd[k] >> BSH;
                pk[m] = ((unsigned)dd[k] << 16) | (unsigned)ss[k];
                rk[m] = (unsigned short)atomicAdd(&h[b], 1);
                bk[m] = (unsigned char)b;
                ++m;
            }
        } else {
            for (int k = 0; k < 4; ++k) {
                if (e + k < E) {
                    int d = dst[e + k], sv = src[e + k];
                    int b = d >> BSH;
                    pk[m] = ((unsigned)d << 16) | (unsigned)sv;
                    rk[m] = (unsigned short)atomicAdd(&h[b], 1);
                    bk[m] = (unsigned char)b;
                    ++m;
                }
            }
        }
    }
    __syncthreads();
    if (tid < nbuk && h[tid]) base[tid] = tid * SLABCAP + atomicAdd(&cursor[tid], h[tid]);
    __syncthreads();
    for (int j2 = 0; j2 < m; ++j2)
        pk_out[base[bk[j2]] + (int)rk[j2]] = pk[j2];
}

// ---------------- CSR build from slabs (counts live in cursor) --------------
__device__ __forceinline__ void csr_body(const unsigned* __restrict__ pk_arr,
                                         const int* __restrict__ cursor,
                                         int* __restrict__ row_ptr,
                                         unsigned short* __restrict__ col_idx,
                                         float* __restrict__ dinv,
                                         int N, int E, int nbuk, int b) {
    __shared__ int hcnt[256];
    __shared__ int esc[256];
    __shared__ int sx[256];
    int tid = threadIdx.x;

    int v = (tid < nbuk) ? cursor[tid] : 0;
    sx[tid] = v;
    __syncthreads();
    int x = v;
    for (int o = 1; o < 256; o <<= 1) {
        int y = (tid >= o) ? sx[tid - o] : 0;
        __syncthreads();
        x += y;
        sx[tid] = x;
        __syncthreads();
    }
    int s0 = (b > 0) ? sx[b - 1] : 0;
    int cnt = sx[b] - s0;
    __syncthreads();

    hcnt[tid] = 0;
    __syncthreads();

    const unsigned* slab = pk_arr + (size_t)b * SLABCAP;
    unsigned p[20];
    unsigned short r[20];
    int m = 0;
    for (int i = tid; i < cnt; i += 256) {
        unsigned pp = slab[i];
        int d = (pp >> 16) & 255;
        r[m] = (unsigned short)atomicAdd(&hcnt[d], 1);
        p[m] = pp;
        ++m;
    }
    __syncthreads();

    int hv = hcnt[tid];
    esc[tid] = hv;
    __syncthreads();
    int hx = hv;
    for (int o = 1; o < 256; o <<= 1) {
        int y = (tid >= o) ? esc[tid - o] : 0;
        __syncthreads();
        hx += y;
        esc[tid] = hx;
        __syncthreads();
    }
    int excl = hx - hv;
    __syncthreads();
    esc[tid] = excl;
    __syncthreads();

    int node = (b << BSH) + tid;
    if (node < N) {
        row_ptr[node] = s0 + excl;
        dinv[node] = rsqrtf((float)(hv + 1));   // +1 self loop
    }
    if (node == N) row_ptr[N] = E;

    for (int j = 0; j < m; ++j) {
        int d = (p[j] >> 16) & 255;
        col_idx[s0 + esc[d] + (int)r[j]] = (unsigned short)(p[j] & 0xFFFFu);
    }
}

// ---------------- GEMM pieces (split-f16 MFMA, prepped fragments) -----------
__device__ __forceinline__ void stage_frags(const _Float16* __restrict__ Whi,
                                            const _Float16* __restrict__ Wlo,
                                            _Float16* __restrict__ WhiS,
                                            _Float16* __restrict__ WloS) {
    const int tid = threadIdx.x;
#pragma unroll
    for (int j = 0; j < 8; ++j)
        ((float4*)WhiS)[tid + j * 256] = ((const float4*)Whi)[tid + j * 256];
#pragma unroll
    for (int j = 0; j < 8; ++j)
        ((float4*)WloS)[tid + j * 256] = ((const float4*)Wlo)[tid + j * 256];
}

template <typename InT>
__device__ __forceinline__ void load_A(const InT* __restrict__ X, int M, int m0,
                                       half8 (&Ahi)[2][4], half8 (&Alo)[2][4]) {
    const int lane = threadIdx.x & 63;
    const int quad = lane >> 4, l16 = lane & 15;
#pragma unroll
    for (int r = 0; r < 2; ++r) {
        int row = m0 + r * 16 + l16;
        row = row < M ? row : (M - 1);
        const InT* xr = X + (size_t)row * 128 + quad * 8;
#pragma unroll
        for (int s = 0; s < 4; ++s) {
            if constexpr (sizeof(InT) == 2) {
                Ahi[r][s] = *(const half8*)(xr + s * 32);   // exact
            } else {
                float4 a = ((const float4*)(xr + s * 32))[0];
                float4 b = ((const float4*)(xr + s * 32))[1];
                float v[8] = {a.x, a.y, a.z, a.w, b.x, b.y, b.z, b.w};
#pragma unroll
                for (int j = 0; j < 8; ++j) {
                    _Float16 hi, lo;
                    split_f16(v[j], hi, lo);
                    Ahi[r][s][j] = hi;
                    Alo[r][s][j] = lo;
                }
            }
        }
    }
}

template <typename OutT, int TERMS, bool BIAS, bool RELU>
__device__ __forceinline__ void mfma_store(half8 (&Ahi)[2][4], half8 (&Alo)[2][4],
                                           const _Float16* __restrict__ WhiS,
                                           const _Float16* __restrict__ WloS,
                                           const float* __restrict__ bias,
                                           OutT* __restrict__ Y, int M, int m0) {
    const int lane = threadIdx.x & 63;
    const int quad = lane >> 4, l16 = lane & 15;

    floatx4 acc[2][8];
#pragma unroll
    for (int r = 0; r < 2; ++r)
#pragma unroll
        for (int t = 0; t < 8; ++t) acc[r][t] = (floatx4){0.f, 0.f, 0.f, 0.f};

    const half8* WH = (const half8*)WhiS;
    const half8* WL = (const half8*)WloS;
#pragma unroll
    for (int s = 0; s < 4; ++s) {
#pragma unroll
        for (int t = 0; t < 8; ++t) {
            half8 bh = WH[(t * 4 + s) * 64 + lane];
            half8 bl = WL[(t * 4 + s) * 64 + lane];
#pragma unroll
            for (int r = 0; r < 2; ++r) {
                acc[r][t] = __builtin_amdgcn_mfma_f32_16x16x32_f16(Ahi[r][s], bh, acc[r][t], 0, 0, 0);
                if constexpr (TERMS == 3)
                    acc[r][t] = __builtin_amdgcn_mfma_f32_16x16x32_f16(Alo[r][s], bh, acc[r][t], 0, 0, 0);
                acc[r][t] = __builtin_amdgcn_mfma_f32_16x16x32_f16(Ahi[r][s], bl, acc[r][t], 0, 0, 0);
            }
        }
    }

    float bcol[8];
    if (BIAS) {
#pragma unroll
        for (int t = 0; t < 8; ++t) bcol[t] = bias[t * 16 + l16];
    }
#pragma unroll
    for (int r = 0; r < 2; ++r) {
#pragma unroll
        for (int e = 0; e < 4; ++e) {
            int row = m0 + r * 16 + quad * 4 + e;
            if (row < M) {
                OutT* yr = Y + (size_t)row * 128 + l16;
#pragma unroll
                for (int t = 0; t < 8; ++t) {
                    float v = acc[r][t][e];
                    if (BIAS) v += bcol[t];
                    if (RELU) v = fmaxf(v, 0.f);
                    if constexpr (sizeof(OutT) == 4) yr[t * 16] = v;
                    else yr[t * 16] = __float2half(v);
                }
            }
        }
    }
}

// ---------------- K2: fused CSR build + layer-0 GEMM ------------------------
__global__ __launch_bounds__(256) void csrgemm_k(const unsigned* __restrict__ pk_arr,
                                                 const int* __restrict__ cursor,
                                                 int* __restrict__ row_ptr,
                                                 unsigned short* __restrict__ col_idx,
                                                 float* __restrict__ dinv,
                                                 const float* __restrict__ X,
                                                 const _Float16* __restrict__ Whi,
                                                 const _Float16* __restrict__ Wlo,
                                                 __half* __restrict__ hs,
                                                 int N, int E, int nbuk) {
    if ((int)blockIdx.x < nbuk) {
        csr_body(pk_arr, cursor, row_ptr, col_idx, dinv, N, E, nbuk, blockIdx.x);
        return;
    }
    __shared__ _Float16 WhiS[16384];
    __shared__ _Float16 WloS[16384];
    stage_frags(Whi, Wlo, WhiS, WloS);
    half8 Ahi[2][4], Alo[2][4];
    int m0 = (blockIdx.x - nbuk) * 128 + ((threadIdx.x >> 6) << 5);
    load_A<float>(X, N, m0, Ahi, Alo);
    __syncthreads();
    mfma_store<__half, 3, false, false>(Ahi, Alo, WhiS, WloS, nullptr, hs, N, m0);
}

// ---------------- K3: fused weighted agg + layer-1 GEMM ---------------------
// Block owns 32 consecutive nodes (one per 16-lane group, 2 halves).
// Phase 1: weighted aggregate (8-deep batches, consume-time weight shfl,
// epilogue bias) -> padded LDS f16 tile (32 rows). Phase 2: two 16-row
// 2-term f16 GEMM tiles sharing each streamed B-fragment (halves W traffic).
#define LP16 136   // f16 elems per LDS row (272B stride -> 2-way banks)
__global__ __launch_bounds__(256, 8) void agg0gemm1_k(const __half* __restrict__ hs,
                                                      const int* __restrict__ row_ptr,
                                                      const unsigned short* __restrict__ col_idx,
                                                      const float* __restrict__ dinv,
                                                      const float* __restrict__ bias,
                                                      const _Float16* __restrict__ W1hi,
                                                      const _Float16* __restrict__ W1lo,
                                                      __half* __restrict__ out_hs, int n) {
    __shared__ _Float16 A[32 * LP16];
    const int tid = threadIdx.x;
    const int c = tid & 15;
    const int g = tid >> 4;
    const int gbase = tid & 48;

#pragma unroll
    for (int hf = 0; hf < 2; ++hf) {
        int i = blockIdx.x * 32 + hf * 16 + g;
        int rl = (hf * 16 + g) * LP16 + c * 8;
        if (i < n) {
            float di = dinv[i];
            float acc[8];
            {
                uint4 raw = ((const uint4*)(hs + (size_t)i * DFEAT))[c];
                const __half2* hp = (const __half2*)&raw;
#pragma unroll
                for (int k = 0; k < 4; ++k) {
                    float2 f = __half22float2(hp[k]);
                    acc[2 * k] = f.x * di; acc[2 * k + 1] = f.y * di;
                }
            }
            int rs = row_ptr[i];
            int cnt = row_ptr[i + 1] - rs;

            for (int base = 0; base < cnt; base += 16) {
                int t = base + c;
                int idx = (t < cnt) ? (int)col_idx[rs + t] : 0;
                float dv = (t < cnt) ? dinv[idx] : 0.f;
                int lim = cnt - base; if (lim > 16) lim = 16;
#pragma unroll
                for (int h = 0; h < 2; ++h) {
                    int l0 = h * 8;
                    if (l0 < lim) {
                        uint4 vv[8];
#pragma unroll
                        for (int q = 0; q < 8; ++q) {
                            int ia = __shfl(idx, gbase + l0 + q);
                            if (l0 + q < lim)
                                vv[q] = ((const uint4*)(hs + (size_t)ia * DFEAT))[c];
                        }
#pragma unroll
                        for (int q = 0; q < 8; ++q) {
                            if (l0 + q < lim) {
                                float wq = __shfl(dv, gbase + l0 + q);
                                const __half2* pq = (const __half2*)&vv[q];
#pragma unroll
                                for (int k = 0; k < 4; ++k) {
                                    float2 f = __half22float2(pq[k]);
                                    acc[2 * k]     = fmaf(f.x, wq, acc[2 * k]);
                                    acc[2 * k + 1] = fmaf(f.y, wq, acc[2 * k + 1]);
                                }
                            }
                        }
                    }
                }
            }

            float4 b0 = ((const float4*)bias)[c * 2];
            float4 b1 = ((const float4*)bias)[c * 2 + 1];
            float o[8];
            o[0] = fmaf(acc[0], di, b0.x); o[1] = fmaf(acc[1], di, b0.y);
            o[2] = fmaf(acc[2], di, b0.z); o[3] = fmaf(acc[3], di, b0.w);
            o[4] = fmaf(acc[4], di, b1.x); o[5] = fmaf(acc[5], di, b1.y);
            o[6] = fmaf(acc[6], di, b1.z); o[7] = fmaf(acc[7], di, b1.w);
            _Float16 hv[8];
#pragma unroll
            for (int k = 0; k < 8; ++k) hv[k] = (_Float16)(fmaxf(o[k], 0.f) * di);
            *(uint4*)(&A[rl]) = *(uint4*)hv;
        } else {
            uint4 z = {0u, 0u, 0u, 0u};
            *(uint4*)(&A[rl]) = z;
        }
    }

    __syncthreads();

    // ---- phase 2: two 16-row tiles share each streamed B fragment ----
    const int lane = tid & 63, wave = tid >> 6;
    const int quad = lane >> 4, l16 = lane & 15;

    floatx4 acc2[2][2];
#pragma unroll
    for (int tile = 0; tile < 2; ++tile) {
        acc2[tile][0] = (floatx4){0.f, 0.f, 0.f, 0.f};
        acc2[tile][1] = (floatx4){0.f, 0.f, 0.f, 0.f};
    }
#pragma unroll
    for (int s = 0; s < 4; ++s) {
#pragma unroll
        for (int tt = 0; tt < 2; ++tt) {
            int t = wave * 2 + tt;
            half8 bh = *(const half8*)(W1hi + ((size_t)((t * 4 + s) * 64 + lane)) * 8);
            half8 bl = *(const half8*)(W1lo + ((size_t)((t * 4 + s) * 64 + lane)) * 8);
#pragma unroll
            for (int tile = 0; tile < 2; ++tile) {
                half8 a = *(const half8*)(&A[(tile * 16 + l16) * LP16 + s * 32 + quad * 8]);
                acc2[tile][tt] = __builtin_amdgcn_mfma_f32_16x16x32_f16(a, bh, acc2[tile][tt], 0, 0, 0);
                acc2[tile][tt] = __builtin_amdgcn_mfma_f32_16x16x32_f16(a, bl, acc2[tile][tt], 0, 0, 0);
            }
        }
    }
#pragma unroll
    for (int tile = 0; tile < 2; ++tile) {
#pragma unroll
        for (int tt = 0; tt < 2; ++tt) {
            int col = (wave * 2 + tt) * 16 + l16;
#pragma unroll
            for (int e = 0; e < 4; ++e) {
                int row = blockIdx.x * 32 + tile * 16 + quad * 4 + e;
                if (row < n)
                    out_hs[(size_t)row * DFEAT + col] = __float2half(acc2[tile][tt][e]);
            }
        }
    }
}

// ---------------- K4: fused plain agg + heads -------------------------------
// Block owns 32 nodes. Phase 1: unweighted aggregate, write out_h, split rows
// into LDS f16 hi/lo tiles. Phase 2: heads sequential; per head two 16-row
// tiles share each streamed B fragment; A read per-MFMA from LDS.
__global__ __launch_bounds__(256, 8) void agg1heads_k(const __half* __restrict__ hs,
                                                      const int* __restrict__ row_ptr,
                                                      const unsigned short* __restrict__ col_idx,
                                                      const float* __restrict__ dinv,
                                                      const float* __restrict__ bias,
                                                      const _Float16* __restrict__ WvHi,
                                                      const _Float16* __restrict__ WvLo,
                                                      const _Float16* __restrict__ WtHi,
                                                      const _Float16* __restrict__ WtLo,
                                                      const float* __restrict__ bv,
                                                      const float* __restrict__ bt,
                                                      float* __restrict__ out_h,
                                                      float* __restrict__ out_v,
                                                      float* __restrict__ out_t, int n) {
    __shared__ _Float16 AHi[32 * LP16];
    __shared__ _Float16 ALo[32 * LP16];
    const int tid = threadIdx.x;
    const int c = tid & 15;
    const int g = tid >> 4;
    const int gbase = tid & 48;

#pragma unroll
    for (int hf = 0; hf < 2; ++hf) {
        int i = blockIdx.x * 32 + hf * 16 + g;
        int rl = (hf * 16 + g) * LP16 + c * 8;
        if (i < n) {
            float acc[8];
            {
                uint4 raw = ((const uint4*)(hs + (size_t)i * DFEAT))[c];
                const __half2* hp = (const __half2*)&raw;
#pragma unroll
                for (int k = 0; k < 4; ++k) {
                    float2 f = __half22float2(hp[k]);
                    acc[2 * k] = f.x; acc[2 * k + 1] = f.y;
                }
            }
            int rs = row_ptr[i];
            int cnt = row_ptr[i + 1] - rs;

            for (int base = 0; base < cnt; base += 16) {
                int t = base + c;
                int idx = (t < cnt) ? (int)col_idx[rs + t] : 0;
                int lim = cnt - base; if (lim > 16) lim = 16;
#pragma unroll
                for (int h = 0; h < 2; ++h) {
                    int l0 = h * 8;
                    if (l0 < lim) {
                        uint4 vv[8];
#pragma unroll
                        for (int q = 0; q < 8; ++q) {
                            int ia = __shfl(idx, gbase + l0 + q);
                            if (l0 + q < lim)
                                vv[q] = ((const uint4*)(hs + (size_t)ia * DFEAT))[c];
                        }
#pragma unroll
                        for (int q = 0; q < 8; ++q) {
                            if (l0 + q < lim) {
                                const __half2* pq = (const __half2*)&vv[q];
#pragma unroll
                                for (int k = 0; k < 4; ++k) {
                                    float2 f = __half22float2(pq[k]);
                                    acc[2 * k]     += f.x;
                                    acc[2 * k + 1] += f.y;
                                }
                            }
                        }
                    }
                }
            }

            float di = dinv[i];
            float4 b0 = ((const float4*)bias)[c * 2];
            float4 b1 = ((const float4*)bias)[c * 2 + 1];
            float o[8];
            o[0] = fmaf(acc[0], di, b0.x); o[1] = fmaf(acc[1], di, b0.y);
            o[2] = fmaf(acc[2], di, b0.z); o[3] = fmaf(acc[3], di, b0.w);
            o[4] = fmaf(acc[4], di, b1.x); o[5] = fmaf(acc[5], di, b1.y);
            o[6] = fmaf(acc[6], di, b1.z); o[7] = fmaf(acc[7], di, b1.w);
            ((float4*)(out_h + (size_t)i * DFEAT))[c * 2] =
                make_float4(o[0], o[1], o[2], o[3]);
            ((float4*)(out_h + (size_t)i * DFEAT))[c * 2 + 1] =
                make_float4(o[4], o[5], o[6], o[7]);
            _Float16 hhi[8], hlo[8];
#pragma unroll
            for (int k = 0; k < 8; ++k) split_f16(o[k], hhi[k], hlo[k]);
            *(uint4*)(&AHi[rl]) = *(uint4*)hhi;
            *(uint4*)(&ALo[rl]) = *(uint4*)hlo;
        } else {
            uint4 z = {0u, 0u, 0u, 0u};
            *(uint4*)(&AHi[rl]) = z;
            *(uint4*)(&ALo[rl]) = z;
        }
    }

    __syncthreads();

    // ---- phase 2: heads sequential; 2 tiles share each B fragment ----
    const int lane = tid & 63, wave = tid >> 6;
    const int quad = lane >> 4, l16 = lane & 15;

#pragma unroll
    for (int hd = 0; hd < 2; ++hd) {
        const _Float16* Hi = hd ? WtHi : WvHi;
        const _Float16* Lo = hd ? WtLo : WvLo;
        const float* bb    = hd ? bt : bv;
        float* outp        = hd ? out_t : out_v;

        floatx4 acc[2][2];
#pragma unroll
        for (int tile = 0; tile < 2; ++tile) {
            acc[tile][0] = (floatx4){0.f, 0.f, 0.f, 0.f};
            acc[tile][1] = (floatx4){0.f, 0.f, 0.f, 0.f};
        }
#pragma unroll
        for (int s = 0; s < 4; ++s) {
#pragma unroll
            for (int tt = 0; tt < 2; ++tt) {
                size_t fi = ((size_t)(((wave * 2 + tt) * 4 + s) * 64 + lane)) * 8;
                half8 bh = *(const half8*)(Hi + fi);
                half8 bl = *(const half8*)(Lo + fi);
#pragma unroll
                for (int tile = 0; tile < 2; ++tile) {
                    int al = (tile * 16 + l16) * LP16 + s * 32 + quad * 8;
                    half8 ahi = *(const half8*)(&AHi[al]);
                    half8 alo = *(const half8*)(&ALo[al]);
                    acc[tile][tt] = __builtin_amdgcn_mfma_f32_16x16x32_f16(ahi, bh, acc[tile][tt], 0, 0, 0);
                    acc[tile][tt] = __builtin_amdgcn_mfma_f32_16x16x32_f16(alo, bh, acc[tile][tt], 0, 0, 0);
                    acc[tile][tt] = __builtin_amdgcn_mfma_f32_16x16x32_f16(ahi, bl, acc[tile][tt], 0, 0, 0);
                }
            }
        }
#pragma unroll
        for (int tile = 0; tile < 2; ++tile) {
#pragma unroll
            for (int tt = 0; tt < 2; ++tt) {
                int col = (wave * 2 + tt) * 16 + l16;
                float bc = bb[col];
#pragma unroll
                for (int e = 0; e < 4; ++e) {
                    int row = blockIdx.x * 32 + tile * 16 + quad * 4 + e;
                    if (row < n)
                        outp[(size_t)row * DFEAT + col] = fmaxf(acc[tile][tt][e] + bc, 0.f);
                }
            }
        }
    }
}

// ---------------------------------------------------------------------------

static inline size_t align_up(size_t x, size_t a) { return (x + a - 1) & ~(a - 1); }

extern "C" void kernel_launch(void* const* d_in, const int* in_sizes, int n_in,
                              void* d_out, int out_size, void* d_ws, size_t ws_size,
                              hipStream_t stream) {
    const float* x  = (const float*)d_in[0];
    const int*   ei = (const int*)d_in[1];
    const float* W0 = (const float*)d_in[2];
    const float* b0 = (const float*)d_in[3];
    const float* W1 = (const float*)d_in[4];
    const float* b1 = (const float*)d_in[5];
    const float* Wv = (const float*)d_in[6];
    const float* bv = (const float*)d_in[7];
    const float* Wt = (const float*)d_in[8];
    const float* bt = (const float*)d_in[9];

    const int N = in_sizes[0] / DFEAT;
    const int E = in_sizes[1] / 2;
    const int* src = ei;
    const int* dst = ei + E;
    const int nbuk = (N + 255) >> BSH;
    const int npb  = (E + BKE - 1) / BKE;
    const int gb   = (N + 127) / 128;
    const int fusB = (N + 31) / 32;

    // workspace carve-up
    char* w = (char*)d_ws;
    int* cursor      = (int*)w; w += align_up((size_t)256 * 4, 256);
    unsigned* pk_arr = (unsigned*)w; w += align_up((size_t)nbuk * SLABCAP * 4, 256);
    int* row_ptr     = (int*)w; w += align_up((size_t)(N + 1) * 4, 256);
    unsigned short* col_idx = (unsigned short*)w; w += align_up((size_t)E * 2, 256);
    float* dinv      = (float*)w; w += align_up((size_t)N * 4, 256);
    _Float16* whi_all = (_Float16*)w; w += align_up(4 * 16384 * 2, 256);
    _Float16* wlo_all = (_Float16*)w; w += align_up(4 * 16384 * 2, 256);
    __half* hs       = (__half*)w; w += align_up((size_t)N * DFEAT * 2, 256);
    __half* hs2      = (__half*)w; w += align_up((size_t)N * DFEAT * 2, 256);

    _Float16* w0hi = whi_all;            _Float16* w0lo = wlo_all;
    _Float16* w1hi = whi_all + 16384;    _Float16* w1lo = wlo_all + 16384;
    _Float16* wvhi = whi_all + 2*16384;  _Float16* wvlo = wlo_all + 2*16384;
    _Float16* wthi = whi_all + 3*16384;  _Float16* wtlo = wlo_all + 3*16384;

    float* out_h = (float*)d_out;
    float* out_v = out_h + (size_t)N * DFEAT;
    float* out_t = out_h + 2 * (size_t)N * DFEAT;

    hipMemsetAsync(cursor, 0, 256 * 4, stream);

    // K1: W prep + slab partition
    prep_part_k<<<256 + npb, 256, 0, stream>>>(src, dst, cursor, pk_arr,
                                               W0, W1, Wv, Wt, whi_all, wlo_all,
                                               E, nbuk);
    // K2: CSR build + unscaled layer-0 GEMM (co-resident)
    csrgemm_k<<<nbuk + gb, 256, 0, stream>>>(pk_arr, cursor, row_ptr, col_idx,
                                             dinv, x, w0hi, w0lo, hs, N, E, nbuk);
    // K3: weighted agg + layer-1 GEMM fused -> hs2
    agg0gemm1_k<<<fusB, 256, 0, stream>>>(hs, row_ptr, col_idx, dinv, b0,
                                          w1hi, w1lo, hs2, N);
    // K4: plain agg + both heads fused -> out_h, out_v, out_t
    agg1heads_k<<<fusB, 256, 0, stream>>>(hs2, row_ptr, col_idx, dinv, b1,
                                          wvhi, wvlo, wthi, wtlo, bv, bt,
                                          out_h, out_v, out_t, N);
}

// Round 10
// 212.088 us; speedup vs baseline: 1.2076x; 1.1304x over previous
//
#include <hip/hip_runtime.h>
#include <hip/hip_fp16.h>
#include <math.h>

// ---------------------------------------------------------------------------
// GCN 2-layer + two heads, fp32 in/out, MI355X.
//   R15: R11 base (16-node fused agg blocks, lean VGPR, 5 dispatches) +
//   FULL-LINE EPILOGUE STORES: every kernel's result rows are staged through
//   LDS and written as complete 256B/512B rows (uint4/float4 per lane).
//   R13/R14 evidence: scalar 4B/2B-per-lane epilogue stores cause L2
//   write-allocate RMW (FETCH +50MB, WRITE up to 2x on gfx950).
// ---------------------------------------------------------------------------

#define DFEAT 128
#define BSH 8            // bucket = dst >> 8 (256 nodes/bucket)
#define BKE 4096         // edges per partition block
#define SLABCAP 4608     // bucket slab capacity: mean 4096 + 8 sigma

using half8   = __attribute__((ext_vector_type(8))) _Float16;
using floatx4 = __attribute__((ext_vector_type(4))) float;

__device__ __forceinline__ void split_f16(float x, _Float16& hi, _Float16& lo) {
    _Float16 h = (_Float16)x;
    hi = h;
    lo = (_Float16)(x - (float)h);
}

// ---------------- K1: W pre-split to f16 frags  +  slab partition -----------
__global__ __launch_bounds__(256) void prep_part_k(const int* __restrict__ src,
                                                   const int* __restrict__ dst,
                                                   int* __restrict__ cursor,
                                                   unsigned* __restrict__ pk_out,
                                                   const float* __restrict__ W0,
                                                   const float* __restrict__ W1,
                                                   const float* __restrict__ W2,
                                                   const float* __restrict__ W3,
                                                   _Float16* __restrict__ hi_all,
                                                   _Float16* __restrict__ lo_all,
                                                   int E, int nbuk) {
    int tid = threadIdx.x;
    if (blockIdx.x < 256) {
        int pb = blockIdx.x;
        int b = pb >> 6;
        const float* W = (b == 0) ? W0 : (b == 1) ? W1 : (b == 2) ? W2 : W3;
        _Float16* hi = hi_all + (size_t)b * 16384;
        _Float16* lo = lo_all + (size_t)b * 16384;
        int i = (pb & 63) * 256 + tid;
        int j = i & 7;
        int lane = (i >> 3) & 63;
        int ts = i >> 9;
        int s = ts & 3, t = ts >> 2;
        int k = s * 32 + (lane >> 4) * 8 + j;
        int n = t * 16 + (lane & 15);
        split_f16(W[k * 128 + n], hi[i], lo[i]);
        return;
    }

    // ---- partition body ----
    __shared__ int h[256];
    __shared__ int base[256];
    h[tid] = 0;
    __syncthreads();
    int B = blockIdx.x - 256;
    int e0 = B * BKE;

    unsigned pk[16];
    unsigned short rk[16];
    unsigned char bk[16];
    int m = 0;
#pragma unroll
    for (int it = 0; it < 4; ++it) {
        int e = e0 + it * 1024 + tid * 4;
        if (e + 3 < E) {
            int4 d4 = *(const int4*)(dst + e);
            int4 s4 = *(const int4*)(src + e);
            int dd[4] = {d4.x, d4.y, d4.z, d4.w};
            int ss[4] = {s4.x, s4.y, s4.z, s4.w};
#pragma unroll
            for (int k = 0; k < 4; ++k) {
                int b = dd[k] >> BSH;
                pk[m] = ((unsigned)dd[k] << 16) | (unsigned)ss[k];
                rk[m] = (unsigned short)atomicAdd(&h[b], 1);
                bk[m] = (unsigned char)b;
                ++m;
            }
        } else {
            for (int k = 0; k < 4; ++k) {
                if (e + k < E) {
                    int d = dst[e + k], sv = src[e + k];
                    int b = d >> BSH;
                    pk[m] = ((unsigned)d << 16) | (unsigned)sv;
                    rk[m] = (unsigned short)atomicAdd(&h[b], 1);
                    bk[m] = (unsigned char)b;
                    ++m;
                }
            }
        }
    }
    __syncthreads();
    if (tid < nbuk && h[tid]) base[tid] = tid * SLABCAP + atomicAdd(&cursor[tid], h[tid]);
    __syncthreads();
    for (int j2 = 0; j2 < m; ++j2)
        pk_out[base[bk[j2]] + (int)rk[j2]] = pk[j2];
}

// ---------------- CSR build from slabs (counts live in cursor) --------------
__device__ __forceinline__ void csr_body(const unsigned* __restrict__ pk_arr,
                                         const int* __restrict__ cursor,
                                         int* __restrict__ row_ptr,
                                         unsigned short* __restrict__ col_idx,
                                         float* __restrict__ dinv,
                                         int N, int E, int nbuk, int b) {
    __shared__ int hcnt[256];
    __shared__ int esc[256];
    __shared__ int sx[256];
    int tid = threadIdx.x;

    int v = (tid < nbuk) ? cursor[tid] : 0;
    sx[tid] = v;
    __syncthreads();
    int x = v;
    for (int o = 1; o < 256; o <<= 1) {
        int y = (tid >= o) ? sx[tid - o] : 0;
        __syncthreads();
        x += y;
        sx[tid] = x;
        __syncthreads();
    }
    int s0 = (b > 0) ? sx[b - 1] : 0;
    int cnt = sx[b] - s0;
    __syncthreads();

    hcnt[tid] = 0;
    __syncthreads();

    const unsigned* slab = pk_arr + (size_t)b * SLABCAP;
    unsigned p[20];
    unsigned short r[20];
    int m = 0;
    for (int i = tid; i < cnt; i += 256) {
        unsigned pp = slab[i];
        int d = (pp >> 16) & 255;
        r[m] = (unsigned short)atomicAdd(&hcnt[d], 1);
        p[m] = pp;
        ++m;
    }
    __syncthreads();

    int hv = hcnt[tid];
    esc[tid] = hv;
    __syncthreads();
    int hx = hv;
    for (int o = 1; o < 256; o <<= 1) {
        int y = (tid >= o) ? esc[tid - o] : 0;
        __syncthreads();
        hx += y;
        esc[tid] = hx;
        __syncthreads();
    }
    int excl = hx - hv;
    __syncthreads();
    esc[tid] = excl;
    __syncthreads();

    int node = (b << BSH) + tid;
    if (node < N) {
        row_ptr[node] = s0 + excl;
        dinv[node] = rsqrtf((float)(hv + 1));   // +1 self loop
    }
    if (node == N) row_ptr[N] = E;

    for (int j = 0; j < m; ++j) {
        int d = (p[j] >> 16) & 255;
        col_idx[s0 + esc[d] + (int)r[j]] = (unsigned short)(p[j] & 0xFFFFu);
    }
}

// ---------------- GEMM pieces (split-f16 MFMA, prepped fragments) -----------
__device__ __forceinline__ void stage_frags(const _Float16* __restrict__ Whi,
                                            const _Float16* __restrict__ Wlo,
                                            _Float16* __restrict__ WhiS,
                                            _Float16* __restrict__ WloS) {
    const int tid = threadIdx.x;
#pragma unroll
    for (int j = 0; j < 8; ++j)
        ((float4*)WhiS)[tid + j * 256] = ((const float4*)Whi)[tid + j * 256];
#pragma unroll
    for (int j = 0; j < 8; ++j)
        ((float4*)WloS)[tid + j * 256] = ((const float4*)Wlo)[tid + j * 256];
}

template <typename InT>
__device__ __forceinline__ void load_A(const InT* __restrict__ X, int M, int m0,
                                       half8 (&Ahi)[2][4], half8 (&Alo)[2][4]) {
    const int lane = threadIdx.x & 63;
    const int quad = lane >> 4, l16 = lane & 15;
#pragma unroll
    for (int r = 0; r < 2; ++r) {
        int row = m0 + r * 16 + l16;
        row = row < M ? row : (M - 1);
        const InT* xr = X + (size_t)row * 128 + quad * 8;
#pragma unroll
        for (int s = 0; s < 4; ++s) {
            if constexpr (sizeof(InT) == 2) {
                Ahi[r][s] = *(const half8*)(xr + s * 32);   // exact
            } else {
                float4 a = ((const float4*)(xr + s * 32))[0];
                float4 b = ((const float4*)(xr + s * 32))[1];
                float v[8] = {a.x, a.y, a.z, a.w, b.x, b.y, b.z, b.w};
#pragma unroll
                for (int j = 0; j < 8; ++j) {
                    _Float16 hi, lo;
                    split_f16(v[j], hi, lo);
                    Ahi[r][s][j] = hi;
                    Alo[r][s][j] = lo;
                }
            }
        }
    }
}

// ---------------- K2: fused CSR build + layer-0 GEMM ------------------------
// GEMM epilogue: acc -> LDS f16 tile [128][136] -> full 256B row stores
// (uint4 per lane) -> no partial-line write-allocate RMW on hs.
__global__ __launch_bounds__(256) void csrgemm_k(const unsigned* __restrict__ pk_arr,
                                                 const int* __restrict__ cursor,
                                                 int* __restrict__ row_ptr,
                                                 unsigned short* __restrict__ col_idx,
                                                 float* __restrict__ dinv,
                                                 const float* __restrict__ X,
                                                 const _Float16* __restrict__ Whi,
                                                 const _Float16* __restrict__ Wlo,
                                                 __half* __restrict__ hs,
                                                 int N, int E, int nbuk) {
    if ((int)blockIdx.x < nbuk) {
        csr_body(pk_arr, cursor, row_ptr, col_idx, dinv, N, E, nbuk, blockIdx.x);
        return;
    }
    __shared__ _Float16 SMEM[32768];   // Whi|Wlo staging, reused for epilogue
    _Float16* WhiS = SMEM;
    _Float16* WloS = SMEM + 16384;
    stage_frags(Whi, Wlo, WhiS, WloS);
    half8 Ahi[2][4], Alo[2][4];
    const int tid = threadIdx.x;
    const int lane = tid & 63, wave = tid >> 6;
    const int quad = lane >> 4, l16 = lane & 15;
    int blk = blockIdx.x - nbuk;
    int m0 = blk * 128 + wave * 32;
    load_A<float>(X, N, m0, Ahi, Alo);
    __syncthreads();

    floatx4 acc[2][8];
#pragma unroll
    for (int r = 0; r < 2; ++r)
#pragma unroll
        for (int t = 0; t < 8; ++t) acc[r][t] = (floatx4){0.f, 0.f, 0.f, 0.f};

    const half8* WH = (const half8*)WhiS;
    const half8* WL = (const half8*)WloS;
#pragma unroll
    for (int s = 0; s < 4; ++s) {
#pragma unroll
        for (int t = 0; t < 8; ++t) {
            half8 bh = WH[(t * 4 + s) * 64 + lane];
            half8 bl = WL[(t * 4 + s) * 64 + lane];
#pragma unroll
            for (int r = 0; r < 2; ++r) {
                acc[r][t] = __builtin_amdgcn_mfma_f32_16x16x32_f16(Ahi[r][s], bh, acc[r][t], 0, 0, 0);
                acc[r][t] = __builtin_amdgcn_mfma_f32_16x16x32_f16(Alo[r][s], bh, acc[r][t], 0, 0, 0);
                acc[r][t] = __builtin_amdgcn_mfma_f32_16x16x32_f16(Ahi[r][s], bl, acc[r][t], 0, 0, 0);
            }
        }
    }

    __syncthreads();   // all W-fragment reads done; SMEM reusable
#pragma unroll
    for (int r = 0; r < 2; ++r)
#pragma unroll
        for (int t = 0; t < 8; ++t)
#pragma unroll
            for (int e = 0; e < 4; ++e)
                SMEM[(wave * 32 + r * 16 + quad * 4 + e) * 136 + t * 16 + l16] =
                    (_Float16)acc[r][t][e];
    __syncthreads();
#pragma unroll
    for (int it = 0; it < 8; ++it) {
        int lr = it * 16 + (tid >> 4);
        int grow = blk * 128 + lr;
        if (grow < N)
            *(uint4*)(hs + (size_t)grow * 128 + (tid & 15) * 8) =
                *(const uint4*)(&SMEM[lr * 136 + (tid & 15) * 8]);
    }
}

// ---------------- K3: fused weighted agg + layer-1 GEMM ---------------------
// Block owns 16 nodes (one per 16-lane group). Phase 1: weighted aggregate
// (8-deep batches, consume-time weight shfl, epilogue bias) -> padded LDS
// f16 tile. Phase 2: 2-term f16 GEMM (B streamed from L2), result staged back
// into the LDS tile -> full 256B row stores.
#define LP16 136   // f16 elems per LDS row (272B stride -> 2-way banks)
__global__ __launch_bounds__(256, 8) void agg0gemm1_k(const __half* __restrict__ hs,
                                                      const int* __restrict__ row_ptr,
                                                      const unsigned short* __restrict__ col_idx,
                                                      const float* __restrict__ dinv,
                                                      const float* __restrict__ bias,
                                                      const _Float16* __restrict__ W1hi,
                                                      const _Float16* __restrict__ W1lo,
                                                      __half* __restrict__ out_hs, int n) {
    __shared__ _Float16 A[16 * LP16];
    const int tid = threadIdx.x;
    const int c = tid & 15;
    const int g = tid >> 4;
    const int gbase = tid & 48;

    int i = blockIdx.x * 16 + g;

    if (i < n) {
        float di = dinv[i];
        float acc[8];
        {
            uint4 raw = ((const uint4*)(hs + (size_t)i * DFEAT))[c];
            const __half2* hp = (const __half2*)&raw;
#pragma unroll
            for (int k = 0; k < 4; ++k) {
                float2 f = __half22float2(hp[k]);
                acc[2 * k] = f.x * di; acc[2 * k + 1] = f.y * di;
            }
        }
        int s = row_ptr[i];
        int cnt = row_ptr[i + 1] - s;

        for (int base = 0; base < cnt; base += 16) {
            int t = base + c;
            int idx = (t < cnt) ? (int)col_idx[s + t] : 0;
            float dv = (t < cnt) ? dinv[idx] : 0.f;
            int lim = cnt - base; if (lim > 16) lim = 16;
#pragma unroll
            for (int h = 0; h < 2; ++h) {
                int l0 = h * 8;
                if (l0 < lim) {
                    uint4 vv[8];
#pragma unroll
                    for (int q = 0; q < 8; ++q) {
                        int ia = __shfl(idx, gbase + l0 + q);
                        if (l0 + q < lim)
                            vv[q] = ((const uint4*)(hs + (size_t)ia * DFEAT))[c];
                    }
#pragma unroll
                    for (int q = 0; q < 8; ++q) {
                        if (l0 + q < lim) {
                            float wq = __shfl(dv, gbase + l0 + q);
                            const __half2* pq = (const __half2*)&vv[q];
#pragma unroll
                            for (int k = 0; k < 4; ++k) {
                                float2 f = __half22float2(pq[k]);
                                acc[2 * k]     = fmaf(f.x, wq, acc[2 * k]);
                                acc[2 * k + 1] = fmaf(f.y, wq, acc[2 * k + 1]);
                            }
                        }
                    }
                }
            }
        }

        float4 b0 = ((const float4*)bias)[c * 2];
        float4 b1 = ((const float4*)bias)[c * 2 + 1];
        float o[8];
        o[0] = fmaf(acc[0], di, b0.x); o[1] = fmaf(acc[1], di, b0.y);
        o[2] = fmaf(acc[2], di, b0.z); o[3] = fmaf(acc[3], di, b0.w);
        o[4] = fmaf(acc[4], di, b1.x); o[5] = fmaf(acc[5], di, b1.y);
        o[6] = fmaf(acc[6], di, b1.z); o[7] = fmaf(acc[7], di, b1.w);
        _Float16 hv[8];
#pragma unroll
        for (int k = 0; k < 8; ++k) hv[k] = (_Float16)(fmaxf(o[k], 0.f) * di);
        *(uint4*)(&A[g * LP16 + c * 8]) = *(uint4*)hv;
    } else {
        uint4 z = {0u, 0u, 0u, 0u};
        *(uint4*)(&A[g * LP16 + c * 8]) = z;
    }

    __syncthreads();

    // ---- phase 2: GEMM (each wave: 2 column blocks of 16) ----
    const int lane = tid & 63, wave = tid >> 6;
    const int quad = lane >> 4, l16 = lane & 15;
    half8 a[4];
#pragma unroll
    for (int s = 0; s < 4; ++s)
        a[s] = *(const half8*)(&A[l16 * LP16 + s * 32 + quad * 8]);

    floatx4 acc2[2];
    acc2[0] = (floatx4){0.f, 0.f, 0.f, 0.f};
    acc2[1] = (floatx4){0.f, 0.f, 0.f, 0.f};
#pragma unroll
    for (int s = 0; s < 4; ++s) {
#pragma unroll
        for (int tt = 0; tt < 2; ++tt) {
            int t = wave * 2 + tt;
            half8 bh = *(const half8*)(W1hi + ((size_t)((t * 4 + s) * 64 + lane)) * 8);
            half8 bl = *(const half8*)(W1lo + ((size_t)((t * 4 + s) * 64 + lane)) * 8);
            acc2[tt] = __builtin_amdgcn_mfma_f32_16x16x32_f16(a[s], bh, acc2[tt], 0, 0, 0);
            acc2[tt] = __builtin_amdgcn_mfma_f32_16x16x32_f16(a[s], bl, acc2[tt], 0, 0, 0);
        }
    }

    __syncthreads();   // all A reads done; stage result into A
#pragma unroll
    for (int tt = 0; tt < 2; ++tt) {
        int col = (wave * 2 + tt) * 16 + l16;
#pragma unroll
        for (int e = 0; e < 4; ++e)
            A[(quad * 4 + e) * LP16 + col] = (_Float16)acc2[tt][e];
    }
    __syncthreads();
    if (i < n)
        *(uint4*)(out_hs + (size_t)i * DFEAT + c * 8) =
            *(const uint4*)(&A[g * LP16 + c * 8]);
}

// ---------------- K4: fused plain agg + heads -------------------------------
// Phase 1: unweighted aggregate, write out_h (full-line float4 pairs) and
// stash rows in fp32 LDS tile. Phase 2: heads sequential; each head's result
// staged back through the LDS tile -> full 512B row stores (no RMW).
#define LP32 132   // f32 elems per LDS row (528B stride -> 2-way banks)
__global__ __launch_bounds__(256, 8) void agg1heads_k(const __half* __restrict__ hs,
                                                      const int* __restrict__ row_ptr,
                                                      const unsigned short* __restrict__ col_idx,
                                                      const float* __restrict__ dinv,
                                                      const float* __restrict__ bias,
                                                      const _Float16* __restrict__ WvHi,
                                                      const _Float16* __restrict__ WvLo,
                                                      const _Float16* __restrict__ WtHi,
                                                      const _Float16* __restrict__ WtLo,
                                                      const float* __restrict__ bv,
                                                      const float* __restrict__ bt,
                                                      float* __restrict__ out_h,
                                                      float* __restrict__ out_v,
                                                      float* __restrict__ out_t, int n) {
    __shared__ float Af[16 * LP32];
    const int tid = threadIdx.x;
    const int c = tid & 15;
    const int g = tid >> 4;
    const int gbase = tid & 48;

    int i = blockIdx.x * 16 + g;

    if (i < n) {
        float acc[8];
        {
            uint4 raw = ((const uint4*)(hs + (size_t)i * DFEAT))[c];
            const __half2* hp = (const __half2*)&raw;
#pragma unroll
            for (int k = 0; k < 4; ++k) {
                float2 f = __half22float2(hp[k]);
                acc[2 * k] = f.x; acc[2 * k + 1] = f.y;
            }
        }
        int s = row_ptr[i];
        int cnt = row_ptr[i + 1] - s;

        for (int base = 0; base < cnt; base += 16) {
            int t = base + c;
            int idx = (t < cnt) ? (int)col_idx[s + t] : 0;
            int lim = cnt - base; if (lim > 16) lim = 16;
#pragma unroll
            for (int h = 0; h < 2; ++h) {
                int l0 = h * 8;
                if (l0 < lim) {
                    uint4 vv[8];
#pragma unroll
                    for (int q = 0; q < 8; ++q) {
                        int ia = __shfl(idx, gbase + l0 + q);
                        if (l0 + q < lim)
                            vv[q] = ((const uint4*)(hs + (size_t)ia * DFEAT))[c];
                    }
#pragma unroll
                    for (int q = 0; q < 8; ++q) {
                        if (l0 + q < lim) {
                            const __half2* pq = (const __half2*)&vv[q];
#pragma unroll
                            for (int k = 0; k < 4; ++k) {
                                float2 f = __half22float2(pq[k]);
                                acc[2 * k]     += f.x;
                                acc[2 * k + 1] += f.y;
                            }
                        }
                    }
                }
            }
        }

        float di = dinv[i];
        float4 b0 = ((const float4*)bias)[c * 2];
        float4 b1 = ((const float4*)bias)[c * 2 + 1];
        float o[8];
        o[0] = fmaf(acc[0], di, b0.x); o[1] = fmaf(acc[1], di, b0.y);
        o[2] = fmaf(acc[2], di, b0.z); o[3] = fmaf(acc[3], di, b0.w);
        o[4] = fmaf(acc[4], di, b1.x); o[5] = fmaf(acc[5], di, b1.y);
        o[6] = fmaf(acc[6], di, b1.z); o[7] = fmaf(acc[7], di, b1.w);
        float4 w0 = make_float4(o[0], o[1], o[2], o[3]);
        float4 w1 = make_float4(o[4], o[5], o[6], o[7]);
        ((float4*)(out_h + (size_t)i * DFEAT))[c * 2] = w0;
        ((float4*)(out_h + (size_t)i * DFEAT))[c * 2 + 1] = w1;
        *(float4*)(&Af[g * LP32 + c * 8]) = w0;
        *(float4*)(&Af[g * LP32 + c * 8 + 4]) = w1;
    } else {
        float4 z = make_float4(0.f, 0.f, 0.f, 0.f);
        *(float4*)(&Af[g * LP32 + c * 8]) = z;
        *(float4*)(&Af[g * LP32 + c * 8 + 4]) = z;
    }

    __syncthreads();

    // ---- phase 2: head GEMMs, sequential (V then T) ----
    const int lane = tid & 63, wave = tid >> 6;
    const int quad = lane >> 4, l16 = lane & 15;
    half8 ahi[4], alo[4];
#pragma unroll
    for (int s = 0; s < 4; ++s) {
        float4 fa = *(const float4*)(&Af[l16 * LP32 + s * 32 + quad * 8]);
        float4 fb = *(const float4*)(&Af[l16 * LP32 + s * 32 + quad * 8 + 4]);
        float v[8] = {fa.x, fa.y, fa.z, fa.w, fb.x, fb.y, fb.z, fb.w};
#pragma unroll
        for (int j = 0; j < 8; ++j) {
            _Float16 hi, lo;
            split_f16(v[j], hi, lo);
            ahi[s][j] = hi;
            alo[s][j] = lo;
        }
    }
    __syncthreads();   // A-fragment reads done; Af reusable as output stage

#pragma unroll
    for (int hd = 0; hd < 2; ++hd) {
        const _Float16* Hi = hd ? WtHi : WvHi;
        const _Float16* Lo = hd ? WtLo : WvLo;
        const float* bb    = hd ? bt : bv;
        float* outp        = hd ? out_t : out_v;

        floatx4 acc[2];
        acc[0] = (floatx4){0.f, 0.f, 0.f, 0.f};
        acc[1] = (floatx4){0.f, 0.f, 0.f, 0.f};
#pragma unroll
        for (int s = 0; s < 4; ++s) {
#pragma unroll
            for (int tt = 0; tt < 2; ++tt) {
                size_t fi = ((size_t)(((wave * 2 + tt) * 4 + s) * 64 + lane)) * 8;
                half8 bh = *(const half8*)(Hi + fi);
                half8 bl = *(const half8*)(Lo + fi);
                acc[tt] = __builtin_amdgcn_mfma_f32_16x16x32_f16(ahi[s], bh, acc[tt], 0, 0, 0);
                acc[tt] = __builtin_amdgcn_mfma_f32_16x16x32_f16(alo[s], bh, acc[tt], 0, 0, 0);
                acc[tt] = __builtin_amdgcn_mfma_f32_16x16x32_f16(ahi[s], bl, acc[tt], 0, 0, 0);
            }
        }
        // stage into Af, then full-line row stores
#pragma unroll
        for (int tt = 0; tt < 2; ++tt) {
            int col = (wave * 2 + tt) * 16 + l16;
            float bc = bb[col];
#pragma unroll
            for (int e = 0; e < 4; ++e)
                Af[(quad * 4 + e) * LP32 + col] = fmaxf(acc[tt][e] + bc, 0.f);
        }
        __syncthreads();
        if (i < n) {
            *(float4*)(outp + (size_t)i * DFEAT + c * 8) =
                *(const float4*)(&Af[g * LP32 + c * 8]);
            *(float4*)(outp + (size_t)i * DFEAT + c * 8 + 4) =
                *(const float4*)(&Af[g * LP32 + c * 8 + 4]);
        }
        __syncthreads();
    }
}

// ---------------------------------------------------------------------------

static inline size_t align_up(size_t x, size_t a) { return (x + a - 1) & ~(a - 1); }

extern "C" void kernel_launch(void* const* d_in, const int* in_sizes, int n_in,
                              void* d_out, int out_size, void* d_ws, size_t ws_size,
                              hipStream_t stream) {
    const float* x  = (const float*)d_in[0];
    const int*   ei = (const int*)d_in[1];
    const float* W0 = (const float*)d_in[2];
    const float* b0 = (const float*)d_in[3];
    const float* W1 = (const float*)d_in[4];
    const float* b1 = (const float*)d_in[5];
    const float* Wv = (const float*)d_in[6];
    const float* bv = (const float*)d_in[7];
    const float* Wt = (const float*)d_in[8];
    const float* bt = (const float*)d_in[9];

    const int N = in_sizes[0] / DFEAT;
    const int E = in_sizes[1] / 2;
    const int* src = ei;
    const int* dst = ei + E;
    const int nbuk = (N + 255) >> BSH;
    const int npb  = (E + BKE - 1) / BKE;
    const int gb   = (N + 127) / 128;
    const int fusB = (N + 15) / 16;

    // workspace carve-up
    char* w = (char*)d_ws;
    int* cursor      = (int*)w; w += align_up((size_t)256 * 4, 256);
    unsigned* pk_arr = (unsigned*)w; w += align_up((size_t)nbuk * SLABCAP * 4, 256);
    int* row_ptr     = (int*)w; w += align_up((size_t)(N + 1) * 4, 256);
    unsigned short* col_idx = (unsigned short*)w; w += align_up((size_t)E * 2, 256);
    float* dinv      = (float*)w; w += align_up((size_t)N * 4, 256);
    _Float16* whi_all = (_Float16*)w; w += align_up(4 * 16384 * 2, 256);
    _Float16* wlo_all = (_Float16*)w; w += align_up(4 * 16384 * 2, 256);
    __half* hs       = (__half*)w; w += align_up((size_t)N * DFEAT * 2, 256);
    __half* hs2      = (__half*)w; w += align_up((size_t)N * DFEAT * 2, 256);

    _Float16* w0hi = whi_all;            _Float16* w0lo = wlo_all;
    _Float16* w1hi = whi_all + 16384;    _Float16* w1lo = wlo_all + 16384;
    _Float16* wvhi = whi_all + 2*16384;  _Float16* wvlo = wlo_all + 2*16384;
    _Float16* wthi = whi_all + 3*16384;  _Float16* wtlo = wlo_all + 3*16384;

    float* out_h = (float*)d_out;
    float* out_v = out_h + (size_t)N * DFEAT;
    float* out_t = out_h + 2 * (size_t)N * DFEAT;

    hipMemsetAsync(cursor, 0, 256 * 4, stream);

    // K1: W prep + slab partition
    prep_part_k<<<256 + npb, 256, 0, stream>>>(src, dst, cursor, pk_arr,
                                               W0, W1, Wv, Wt, whi_all, wlo_all,
                                               E, nbuk);
    // K2: CSR build + unscaled layer-0 GEMM (co-resident)
    csrgemm_k<<<nbuk + gb, 256, 0, stream>>>(pk_arr, cursor, row_ptr, col_idx,
                                             dinv, x, w0hi, w0lo, hs, N, E, nbuk);
    // K3: weighted agg + layer-1 GEMM fused -> hs2
    agg0gemm1_k<<<fusB, 256, 0, stream>>>(hs, row_ptr, col_idx, dinv, b0,
                                          w1hi, w1lo, hs2, N);
    // K4: plain agg + both heads fused -> out_h, out_v, out_t
    agg1heads_k<<<fusB, 256, 0, stream>>>(hs2, row_ptr, col_idx, dinv, b1,
                                          wvhi, wvlo, wthi, wtlo, bv, bt,
                                          out_h, out_v, out_t, N);
}